// Round 3
// baseline (1361.018 us; speedup 1.0000x reference)
//
#include <hip/hip_runtime.h>

// Soft-DTW gradient, batch=64, 256x256, gamma=0.01 — single fused kernel.
// One 64-lane wave per batch element; lane t owns rows 4t+1..4t+4 (1-based).
// Skewed column wavefront: lane t computes column c at step s=c-1+t (fwd)
// / s=319-c-t (bwd). Cross-lane dep = one boundary row -> shuffles only.
// Forward stores softmin value A(i,j)=V-theta to ws (same-thread read in
// backward). Backward accumulates E directly into out via device-scope
// atomicAdd (R1-proven replay-safe path; no cross-kernel ws dataflow).

#define MM 256
#define NN 256
#define R 4
#define NL 64
#define BIGV 1.0e10f
#define K2   144.269504089f     // (1/gamma) * log2(e)
#define GLN2 0.00693147181f     // gamma * ln(2)

__device__ __forceinline__ float pick(const float4& v, int ph) {
    float r = v.x;
    r = (ph == 1) ? v.y : r;
    r = (ph == 2) ? v.z : r;
    r = (ph == 3) ? v.w : r;
    return r;
}
__device__ __forceinline__ void put(float4& v, int ph, float x) {
    if (ph == 0) v.x = x;
    else if (ph == 1) v.y = x;
    else if (ph == 2) v.z = x;
    else v.w = x;
}

__global__ __launch_bounds__(64) void dtw_fused(
    const float* __restrict__ D,
    float* __restrict__ out,          // [256][256], pre-zeroed on stream
    float* __restrict__ ws,           // A: [B][256][256] fp32
    float inv_batch)
{
    const int b = blockIdx.x;
    const int t = threadIdx.x;                       // lane 0..63
    const float* __restrict__ th = D + (size_t)b * (MM * NN);
    float* __restrict__ A = ws + (size_t)b * (MM * NN);

    // ---------------- forward ----------------
    {
        float vprev[R];                              // V(row r, c-1)
        #pragma unroll
        for (int r = 0; r < R; ++r) vprev[r] = BIGV; // V(i,0) = BIG
        float topNew = BIGV, topOld = BIGV;          // V(4t, c), V(4t, c-1)
        float bottomV = BIGV;
        float4 cur[R], nxt[R], abuf[R];
        #pragma unroll
        for (int r = 0; r < R; ++r) {
            const float4* rp = (const float4*)(th + (t * R + r) * NN);
            cur[r] = rp[0];
            nxt[r] = rp[1];
        }
        for (int s = 0; s < NN + NL - 1; ++s) {
            const int c = s - t + 1;
            if (c >= 1 && c <= NN) {
                const int ph = (c - 1) & 3;
                const int g  = (c - 1) >> 2;
                float aboveOld = (t == 0) ? ((c == 1) ? 0.0f : BIGV) : topOld;
                float aboveNew = (t == 0) ? BIGV : topNew;
                #pragma unroll
                for (int r = 0; r < R; ++r) {
                    const float vl = vprev[r];       // V(i, c-1)
                    const float vd = aboveOld;       // V(i-1, c-1)
                    const float vu = aboveNew;       // V(i-1, c)
                    const float mn = fminf(vl, fminf(vd, vu));
                    const float ssum = exp2f((mn - vl) * K2)
                                     + exp2f((mn - vd) * K2)
                                     + exp2f((mn - vu) * K2);
                    const float a = mn - GLN2 * log2f(ssum);   // softmin value
                    const float v = a + pick(cur[r], ph);      // V(i,c)
                    put(abuf[r], ph, a);
                    aboveOld = vprev[r];
                    aboveNew = v;
                    vprev[r] = v;
                }
                bottomV = vprev[R - 1];
                if (ph == 3) {                       // group done: store A, advance prefetch
                    #pragma unroll
                    for (int r = 0; r < R; ++r) {
                        *(float4*)(A + (t * R + r) * NN + g * 4) = abuf[r];
                        cur[r] = nxt[r];
                    }
                    if (g + 2 <= NN / 4 - 1) {
                        #pragma unroll
                        for (int r = 0; r < R; ++r)
                            nxt[r] = *(const float4*)(th + (t * R + r) * NN + (g + 2) * 4);
                    }
                }
            }
            topOld = topNew;
            topNew = __shfl_up(bottomV, 1);
        }
    }

    __threadfence();   // order forward A-stores before backward A-loads

    // ---------------- backward (E accumulated straight into out) ----------------
    {
        float eprev[R], aprev[R];                    // E/A(row r, c+1)
        #pragma unroll
        for (int r = 0; r < R; ++r) { eprev[r] = 0.0f; aprev[r] = 0.0f; }
        float shA_new = 0.0f, shE_new = 0.0f;        // lane t+1 top row at col c
        float shA_old = 0.0f, shE_old = 0.0f;        // ... at col c+1
        float4 curA[R], nxtA[R], curT[R], nxtT[R], ebuf[R];
        #pragma unroll
        for (int r = 0; r < R; ++r) {
            const float4* ra = (const float4*)(A + (t * R + r) * NN);
            const float4* rt = (const float4*)(th + (t * R + r) * NN);
            curA[r] = ra[NN / 4 - 1];
            nxtA[r] = ra[NN / 4 - 2];
            curT[r] = rt[NN / 4 - 1];
            nxtT[r] = rt[NN / 4 - 2];
        }
        for (int s = 0; s < NN + NL - 1; ++s) {
            const int c = (NN + NL - 1) - s - t;     // 319 - s - t
            if (c >= 1 && c <= NN) {
                const int ph = (c - 1) & 3;
                const int g  = (c - 1) >> 2;
                float belowA_new = (t == NL - 1) ? 0.0f : shA_new;  // A(i+1, c)
                float belowE_new = (t == NL - 1) ? 0.0f : shE_new;  // E(i+1, c)
                float belowA_old = (t == NL - 1) ? 0.0f : shA_old;  // A(i+1, c+1)
                float belowE_old = (t == NL - 1) ? 0.0f : shE_old;  // E(i+1, c+1)
                #pragma unroll
                for (int r = R - 1; r >= 0; --r) {
                    const float aown = pick(curA[r], ph);
                    const float vown = aown + pick(curT[r], ph);    // V(i,c)
                    float e = exp2f((aprev[r]   - vown) * K2) * eprev[r]     // (i,   c+1)
                            + exp2f((belowA_old - vown) * K2) * belowE_old   // (i+1, c+1)
                            + exp2f((belowA_new - vown) * K2) * belowE_new;  // (i+1, c)
                    if (t == NL - 1 && r == R - 1 && c == NN) e = 1.0f;      // seed E(M,N)
                    put(ebuf[r], ph, e);
                    belowA_old = aprev[r];
                    belowE_old = eprev[r];
                    belowA_new = aown;
                    belowE_new = e;
                    aprev[r] = aown;
                    eprev[r] = e;
                }
                if (ph == 0) {                       // group done: flush E, advance prefetch
                    #pragma unroll
                    for (int r = 0; r < R; ++r) {
                        float* op = out + (t * R + r) * NN + g * 4;
                        atomicAdd(op + 0, ebuf[r].x * inv_batch);
                        atomicAdd(op + 1, ebuf[r].y * inv_batch);
                        atomicAdd(op + 2, ebuf[r].z * inv_batch);
                        atomicAdd(op + 3, ebuf[r].w * inv_batch);
                        curA[r] = nxtA[r];
                        curT[r] = nxtT[r];
                    }
                    if (g - 2 >= 0) {
                        #pragma unroll
                        for (int r = 0; r < R; ++r) {
                            nxtA[r] = *(const float4*)(A + (t * R + r) * NN + (g - 2) * 4);
                            nxtT[r] = *(const float4*)(th + (t * R + r) * NN + (g - 2) * 4);
                        }
                    }
                }
            }
            shA_old = shA_new; shE_old = shE_new;
            shA_new = __shfl_down(aprev[0], 1);
            shE_new = __shfl_down(eprev[0], 1);
        }
    }
}

extern "C" void kernel_launch(void* const* d_in, const int* in_sizes, int n_in,
                              void* d_out, int out_size, void* d_ws, size_t ws_size,
                              hipStream_t stream) {
    const float* D = (const float*)d_in[0];
    float* out = (float*)d_out;
    float* ws = (float*)d_ws;
    const int B = in_sizes[0] / (MM * NN);   // 64

    hipMemsetAsync(d_out, 0, (size_t)out_size * sizeof(float), stream);
    dtw_fused<<<dim3(B), dim3(NL), 0, stream>>>(D, out, ws, 1.0f / (float)B);
}

// Round 4
// 597.585 us; speedup vs baseline: 2.2775x; 2.2775x over previous
//
#include <hip/hip_runtime.h>

// Soft-DTW gradient, batch=64, 256x256, gamma=0.01 — single fused kernel.
// One 64-lane wave per batch element; lane t owns rows 4t+1..4t+4 (1-based).
// 4-column skew: lane t processes column-group g (cols 4g+1..4g+4) at
// macro-step m = g + t (forward) / m = 126 - g - t (backward) -> group phase
// is wave-uniform: loads/stores/atomics/shuffles once per 16-cell macro-step,
// prefetch distance 2 macro-steps. Cross-lane dep = one boundary row via
// shuffles. Lane t reads back only A-rows it wrote itself (same-thread).
// Backward accumulates E into out via device-scope atomicAdd (replay-safe).

#define MM 256
#define NN 256
#define R 4
#define NL 64
#define BIGV 1.0e10f
#define K2   144.269504089f     // (1/gamma) * log2(e)
#define GLN2 0.00693147181f     // gamma * ln(2)

__device__ __forceinline__ float f4get(const float4& v, int k) {
    switch (k) { case 0: return v.x; case 1: return v.y; case 2: return v.z; default: return v.w; }
}
__device__ __forceinline__ int iclamp(int x, int lo, int hi) {
    return x < lo ? lo : (x > hi ? hi : x);
}

__global__ __launch_bounds__(64) void dtw_fused(
    const float* __restrict__ D,
    float* __restrict__ out,          // [256][256], pre-zeroed on stream
    float* __restrict__ ws,           // A: [B][256][256] fp32
    float inv_batch)
{
    const int b = blockIdx.x;
    const int t = threadIdx.x;                       // lane 0..63
    const float* __restrict__ th = D + (size_t)b * (MM * NN);
    float* __restrict__ Aws = ws + (size_t)b * (MM * NN);

    // ---------------- forward ----------------
    {
        float vprev[R];                              // V(row r, current left col)
        #pragma unroll
        for (int r = 0; r < R; ++r) vprev[r] = BIGV; // V(i,0) = BIG
        float4 thCur[R], thN1[R], thN2[R];
        #pragma unroll
        for (int r = 0; r < R; ++r) {
            thCur[r] = make_float4(0.f,0.f,0.f,0.f);
            thN1[r]  = make_float4(0.f,0.f,0.f,0.f);
        }
        float4 rec = make_float4(BIGV, BIGV, BIGV, BIGV);  // lane t-1 bottom row, its last group
        float prevW = BIGV;                                 // .w of rec from 2 steps ago
        float botV[4] = {BIGV, BIGV, BIGV, BIGV};

        for (int m = -2; m <= 126; ++m) {
            const int g = m - t;                     // this lane's group
            const int gl = iclamp(g + 2, 0, 63);     // prefetch group (clamped -> always legal)
            #pragma unroll
            for (int r = 0; r < R; ++r)
                thN2[r] = *(const float4*)(th + (4 * t + r) * NN + 4 * gl);

            if (g >= 0 && g <= 63) {
                float4 topV = rec;                   // V(4t, 4g+1..4g+4)
                if (t == 0) topV = make_float4(BIGV, BIGV, BIGV, BIGV);
                const float vd0 = (t == 0) ? ((g == 0) ? 0.0f : BIGV)
                                           : ((g == 0) ? BIGV : prevW);  // V(4t, 4g)
                float abuf[R][4];
                #pragma unroll
                for (int cc = 0; cc < 4; ++cc) {
                    float vu = f4get(topV, cc);                       // V(i-1, c)
                    float vd = (cc == 0) ? vd0 : f4get(topV, cc - 1); // V(i-1, c-1)
                    #pragma unroll
                    for (int r = 0; r < R; ++r) {
                        const float vl = vprev[r];                    // V(i, c-1)
                        const float mn = fminf(vl, fminf(vd, vu));
                        const float ssum = exp2f((mn - vl) * K2)
                                         + exp2f((mn - vd) * K2)
                                         + exp2f((mn - vu) * K2);
                        const float a = mn - GLN2 * log2f(ssum);      // softmin value
                        const float v = a + f4get(thCur[r], cc);      // V(i,c)
                        abuf[r][cc] = a;
                        vd = vl;
                        vu = v;
                        vprev[r] = v;
                    }
                    botV[cc] = vprev[R - 1];
                }
                #pragma unroll
                for (int r = 0; r < R; ++r)
                    *(float4*)(Aws + (4 * t + r) * NN + 4 * g) =
                        make_float4(abuf[r][0], abuf[r][1], abuf[r][2], abuf[r][3]);
            }
            prevW = rec.w;
            rec.x = __shfl_up(botV[0], 1);
            rec.y = __shfl_up(botV[1], 1);
            rec.z = __shfl_up(botV[2], 1);
            rec.w = __shfl_up(botV[3], 1);
            #pragma unroll
            for (int r = 0; r < R; ++r) { thCur[r] = thN1[r]; thN1[r] = thN2[r]; }
        }
    }

    __threadfence();   // order forward A-stores before backward A-loads

    // ---------------- backward ----------------
    {
        float aprev[R], eprev[R];                    // A/E(row r, col c+1)
        #pragma unroll
        for (int r = 0; r < R; ++r) { aprev[r] = 0.0f; eprev[r] = 0.0f; }
        float4 Acur[R], AN1[R], AN2[R], Tcur[R], TN1[R], TN2[R];
        #pragma unroll
        for (int r = 0; r < R; ++r) {
            Acur[r] = make_float4(0.f,0.f,0.f,0.f); AN1[r] = Acur[r];
            Tcur[r] = Acur[r]; TN1[r] = Acur[r];
        }
        float4 recA = make_float4(0.f,0.f,0.f,0.f);  // lane t+1 top row A, its group
        float4 recE = make_float4(0.f,0.f,0.f,0.f);
        float prevAx = 0.0f, prevEx = 0.0f;          // .x of rec from 2 steps ago
        float4 topA = make_float4(0.f,0.f,0.f,0.f);  // sender side: own r=0 A
        float topE[4] = {0.f, 0.f, 0.f, 0.f};        // sender side: own r=0 E

        for (int m = -2; m <= 126; ++m) {
            const int g = 126 - m - t;
            const int gl = iclamp(g - 2, 0, 63);
            #pragma unroll
            for (int r = 0; r < R; ++r) {
                AN2[r] = *(const float4*)(Aws + (4 * t + r) * NN + 4 * gl);
                TN2[r] = *(const float4*)(th  + (4 * t + r) * NN + 4 * gl);
            }
            if (g >= 0 && g <= 63) {
                float4 rA = recA, rE = recE;
                if (t == NL - 1) { rA = make_float4(0.f,0.f,0.f,0.f); rE = rA; }
                const float pAx = (g == 63 || t == NL - 1) ? 0.0f : prevAx;
                const float pEx = (g == 63 || t == NL - 1) ? 0.0f : prevEx;
                float ebuf[R][4];
                #pragma unroll
                for (int cc = 3; cc >= 0; --cc) {
                    float bAn = f4get(rA, cc);                         // A(i+1, c)
                    float bEn = f4get(rE, cc);
                    float bAo = (cc == 3) ? pAx : f4get(rA, cc + 1);   // A(i+1, c+1)
                    float bEo = (cc == 3) ? pEx : f4get(rE, cc + 1);
                    #pragma unroll
                    for (int r = R - 1; r >= 0; --r) {
                        const float aown = f4get(Acur[r], cc);
                        const float vown = aown + f4get(Tcur[r], cc);  // V(i,c)
                        float e = exp2f((aprev[r] - vown) * K2) * eprev[r] // (i, c+1)
                                + exp2f((bAo - vown) * K2) * bEo           // (i+1, c+1)
                                + exp2f((bAn - vown) * K2) * bEn;          // (i+1, c)
                        if (t == NL - 1 && r == R - 1 && g == 63 && cc == 3)
                            e = 1.0f;                                  // seed E(M,N)
                        ebuf[r][cc] = e;
                        bAo = aprev[r]; bEo = eprev[r];
                        bAn = aown;     bEn = e;
                        aprev[r] = aown; eprev[r] = e;
                    }
                }
                topA = Acur[0];
                #pragma unroll
                for (int cc = 0; cc < 4; ++cc) topE[cc] = ebuf[0][cc];
                #pragma unroll
                for (int r = 0; r < R; ++r) {
                    float* op = out + (4 * t + r) * NN + 4 * g;
                    atomicAdd(op + 0, ebuf[r][0] * inv_batch);
                    atomicAdd(op + 1, ebuf[r][1] * inv_batch);
                    atomicAdd(op + 2, ebuf[r][2] * inv_batch);
                    atomicAdd(op + 3, ebuf[r][3] * inv_batch);
                }
            }
            prevAx = recA.x; prevEx = recE.x;
            recA.x = __shfl_down(topA.x, 1);
            recA.y = __shfl_down(topA.y, 1);
            recA.z = __shfl_down(topA.z, 1);
            recA.w = __shfl_down(topA.w, 1);
            recE.x = __shfl_down(topE[0], 1);
            recE.y = __shfl_down(topE[1], 1);
            recE.z = __shfl_down(topE[2], 1);
            recE.w = __shfl_down(topE[3], 1);
            #pragma unroll
            for (int r = 0; r < R; ++r) {
                Acur[r] = AN1[r]; AN1[r] = AN2[r];
                Tcur[r] = TN1[r]; TN1[r] = TN2[r];
            }
        }
    }
}

extern "C" void kernel_launch(void* const* d_in, const int* in_sizes, int n_in,
                              void* d_out, int out_size, void* d_ws, size_t ws_size,
                              hipStream_t stream) {
    const float* D = (const float*)d_in[0];
    float* out = (float*)d_out;
    float* ws = (float*)d_ws;
    const int B = in_sizes[0] / (MM * NN);   // 64

    hipMemsetAsync(d_out, 0, (size_t)out_size * sizeof(float), stream);
    dtw_fused<<<dim3(B), dim3(NL), 0, stream>>>(D, out, ws, 1.0f / (float)B);
}

// Round 5
// 553.595 us; speedup vs baseline: 2.4585x; 1.0795x over previous
//
#include <hip/hip_runtime.h>

// Soft-DTW gradient, batch=64, 256x256, gamma=0.01 — single fused kernel.
// One 64-lane wave per batch element; lane t owns rows 4t+1..4t+4 (1-based).
// 4-column skew (wave-uniform phase): lane t processes column-group g at
// macro-step m = g + t (fwd) / m = 126 - g - t (bwd).
// Forward computes softmin AND its weights (w = e_i / ssum); stores (wl, wu)
// fp32 planes (wd = 1 - wl - wu reconstructed). Backward weight
// exp((A(s)-V(pred))/gamma) == forward weight at s, so backward is pure FMA:
// E(i,j) = wl(i,j+1)E(i,j+1) + wd(i+1,j+1)E(i+1,j+1) + wu(i+1,j)E(i+1,j).
// #pragma unroll 3 removes register-rotation copies -> loads wait 2 iters.
// E accumulated into out via device-scope atomicAdd (replay-safe).

#define MM 256
#define NN 256
#define R 4
#define NL 64
#define BIGV 1.0e10f
#define K2   144.269504089f     // (1/gamma) * log2(e)
#define GLN2 0.00693147181f     // gamma * ln(2)

__device__ __forceinline__ float f4get(const float4& v, int k) {
    switch (k) { case 0: return v.x; case 1: return v.y; case 2: return v.z; default: return v.w; }
}
__device__ __forceinline__ int iclamp(int x, int lo, int hi) {
    return x < lo ? lo : (x > hi ? hi : x);
}
__device__ __forceinline__ float fast_rcp(float x) {
#if __has_builtin(__builtin_amdgcn_rcpf)
    return __builtin_amdgcn_rcpf(x);
#else
    return 1.0f / x;
#endif
}

__global__ __launch_bounds__(64) void dtw_fused(
    const float* __restrict__ D,
    float* __restrict__ out,          // [256][256], pre-zeroed on stream
    float* __restrict__ ws,           // Wl plane then Wu plane, [B][256][256] each
    float inv_batch)
{
    const int b = blockIdx.x;
    const int t = threadIdx.x;                       // lane 0..63
    const float* __restrict__ th = D + (size_t)b * (MM * NN);
    float* __restrict__ Wl = ws + (size_t)b * (MM * NN);
    float* __restrict__ Wu = ws + (size_t)NL * (MM * NN) + (size_t)b * (MM * NN);

    // ---------------- forward ----------------
    {
        float vprev[R];                              // V(row r, current left col)
        #pragma unroll
        for (int r = 0; r < R; ++r) vprev[r] = BIGV; // V(i,0) = BIG
        float4 thCur[R], thN1[R], thN2[R];
        #pragma unroll
        for (int r = 0; r < R; ++r) {
            thCur[r] = make_float4(0.f,0.f,0.f,0.f);
            thN1[r]  = make_float4(0.f,0.f,0.f,0.f);
        }
        float4 rec = make_float4(BIGV, BIGV, BIGV, BIGV);  // lane t-1 bottom row
        float prevW = BIGV;
        float botV[4] = {BIGV, BIGV, BIGV, BIGV};

        #pragma unroll 3
        for (int m = -2; m <= 126; ++m) {
            const int g = m - t;
            const int gl = iclamp(g + 2, 0, 63);
            #pragma unroll
            for (int r = 0; r < R; ++r)
                thN2[r] = *(const float4*)(th + (4 * t + r) * NN + 4 * gl);

            if (g >= 0 && g <= 63) {
                float4 topV = rec;                   // V(4t, 4g+1..4g+4)
                if (t == 0) topV = make_float4(BIGV, BIGV, BIGV, BIGV);
                const float vd0 = (t == 0) ? ((g == 0) ? 0.0f : BIGV)
                                           : ((g == 0) ? BIGV : prevW);  // V(4t, 4g)
                float wlb[R][4], wub[R][4];
                #pragma unroll
                for (int cc = 0; cc < 4; ++cc) {
                    float vu = f4get(topV, cc);                       // V(i-1, c)
                    float vd = (cc == 0) ? vd0 : f4get(topV, cc - 1); // V(i-1, c-1)
                    #pragma unroll
                    for (int r = 0; r < R; ++r) {
                        const float vl = vprev[r];                    // V(i, c-1)
                        const float mn = fminf(vl, fminf(vd, vu));
                        const float el = exp2f((mn - vl) * K2);
                        const float ed = exp2f((mn - vd) * K2);
                        const float eu = exp2f((mn - vu) * K2);
                        const float ss = el + ed + eu;
                        const float ri = fast_rcp(ss);
                        const float a  = mn - GLN2 * log2f(ss);       // softmin value
                        const float v  = a + f4get(thCur[r], cc);     // V(i,c)
                        wlb[r][cc] = el * ri;
                        wub[r][cc] = eu * ri;
                        vd = vl;
                        vu = v;
                        vprev[r] = v;
                    }
                    botV[cc] = vprev[R - 1];
                }
                #pragma unroll
                for (int r = 0; r < R; ++r) {
                    *(float4*)(Wl + (4 * t + r) * NN + 4 * g) =
                        make_float4(wlb[r][0], wlb[r][1], wlb[r][2], wlb[r][3]);
                    *(float4*)(Wu + (4 * t + r) * NN + 4 * g) =
                        make_float4(wub[r][0], wub[r][1], wub[r][2], wub[r][3]);
                }
            }
            prevW = rec.w;
            rec.x = __shfl_up(botV[0], 1);
            rec.y = __shfl_up(botV[1], 1);
            rec.z = __shfl_up(botV[2], 1);
            rec.w = __shfl_up(botV[3], 1);
            #pragma unroll
            for (int r = 0; r < R; ++r) { thCur[r] = thN1[r]; thN1[r] = thN2[r]; }
        }
    }

    __threadfence();   // order forward weight-stores before backward loads

    // ---------------- backward (pure FMA) ----------------
    {
        float eprev[R];                              // E(row r, col c+1)
        float prevWl[R], prevWu[R];                  // own-row W at next group's col0
        #pragma unroll
        for (int r = 0; r < R; ++r) { eprev[r] = 0.0f; prevWl[r] = 0.0f; prevWu[r] = 0.0f; }
        float4 WlC[R], WlN1[R], WlN2[R], WuC[R], WuN1[R], WuN2[R];
        #pragma unroll
        for (int r = 0; r < R; ++r) {
            WlC[r] = make_float4(0.f,0.f,0.f,0.f); WlN1[r] = WlC[r];
            WuC[r] = WlC[r]; WuN1[r] = WlC[r];
        }
        float4 recWd = make_float4(0.f,0.f,0.f,0.f); // lane t+1 row0: wd, wu, E of its group
        float4 recWu = recWd;
        float4 recE  = recWd;
        float pWd = 0.0f, pE = 0.0f;                 // .x of rec from 2 steps ago
        float topWd[4] = {0.f,0.f,0.f,0.f};
        float topWu[4] = {0.f,0.f,0.f,0.f};
        float topE[4]  = {0.f,0.f,0.f,0.f};

        #pragma unroll 3
        for (int m = -2; m <= 126; ++m) {
            const int g = 126 - m - t;
            const int gl = iclamp(g - 2, 0, 63);
            #pragma unroll
            for (int r = 0; r < R; ++r) {
                WlN2[r] = *(const float4*)(Wl + (4 * t + r) * NN + 4 * gl);
                WuN2[r] = *(const float4*)(Wu + (4 * t + r) * NN + 4 * gl);
            }
            if (g >= 0 && g <= 63) {
                float4 rWd = recWd, rWu = recWu, rE = recE;
                if (t == NL - 1) {
                    rWd = make_float4(0.f,0.f,0.f,0.f); rWu = rWd; rE = rWd;
                }
                const float pWd_ = (g == 63 || t == NL - 1) ? 0.0f : pWd;
                const float pE_  = (g == 63 || t == NL - 1) ? 0.0f : pE;
                float ebuf[R][4];
                #pragma unroll
                for (int cc = 3; cc >= 0; --cc) {
                    float bWd = (cc == 3) ? pWd_ : f4get(rWd, cc + 1);  // wd(i+1, c+1)
                    float bEo = (cc == 3) ? pE_  : f4get(rE,  cc + 1);  // E (i+1, c+1)
                    float bWu = f4get(rWu, cc);                         // wu(i+1, c)
                    float bEn = f4get(rE,  cc);                         // E (i+1, c)
                    #pragma unroll
                    for (int r = R - 1; r >= 0; --r) {
                        const float wlr = (cc == 3) ? prevWl[r] : f4get(WlC[r], cc + 1);
                        float e = wlr * eprev[r] + bWd * bEo + bWu * bEn;
                        if (t == NL - 1 && r == R - 1 && g == 63 && cc == 3)
                            e = 1.0f;                                   // seed E(M,N)
                        ebuf[r][cc] = e;
                        // prepare "below row" values for r-1 (its below = row r)
                        const float wl_b = (cc == 3) ? prevWl[r] : f4get(WlC[r], cc + 1);
                        const float wu_b = (cc == 3) ? prevWu[r] : f4get(WuC[r], cc + 1);
                        bWd = 1.0f - wl_b - wu_b;                       // wd(r, c+1)
                        bWu = f4get(WuC[r], cc);                        // wu(r, c)
                        bEo = eprev[r];                                 // E(r, c+1)
                        bEn = e;                                        // E(r, c)
                        eprev[r] = e;
                    }
                }
                #pragma unroll
                for (int cc = 0; cc < 4; ++cc) {
                    topWd[cc] = 1.0f - f4get(WlC[0], cc) - f4get(WuC[0], cc);
                    topWu[cc] = f4get(WuC[0], cc);
                    topE[cc]  = ebuf[0][cc];
                }
                #pragma unroll
                for (int r = 0; r < R; ++r) {
                    float* op = out + (4 * t + r) * NN + 4 * g;
                    atomicAdd(op + 0, ebuf[r][0] * inv_batch);
                    atomicAdd(op + 1, ebuf[r][1] * inv_batch);
                    atomicAdd(op + 2, ebuf[r][2] * inv_batch);
                    atomicAdd(op + 3, ebuf[r][3] * inv_batch);
                }
            }
            pWd = recWd.x; pE = recE.x;
            #pragma unroll
            for (int r = 0; r < R; ++r) { prevWl[r] = WlC[r].x; prevWu[r] = WuC[r].x; }
            recWd.x = __shfl_down(topWd[0], 1);
            recWd.y = __shfl_down(topWd[1], 1);
            recWd.z = __shfl_down(topWd[2], 1);
            recWd.w = __shfl_down(topWd[3], 1);
            recWu.x = __shfl_down(topWu[0], 1);
            recWu.y = __shfl_down(topWu[1], 1);
            recWu.z = __shfl_down(topWu[2], 1);
            recWu.w = __shfl_down(topWu[3], 1);
            recE.x  = __shfl_down(topE[0], 1);
            recE.y  = __shfl_down(topE[1], 1);
            recE.z  = __shfl_down(topE[2], 1);
            recE.w  = __shfl_down(topE[3], 1);
            #pragma unroll
            for (int r = 0; r < R; ++r) {
                WlC[r] = WlN1[r]; WlN1[r] = WlN2[r];
                WuC[r] = WuN1[r]; WuN1[r] = WuN2[r];
            }
        }
    }
}

extern "C" void kernel_launch(void* const* d_in, const int* in_sizes, int n_in,
                              void* d_out, int out_size, void* d_ws, size_t ws_size,
                              hipStream_t stream) {
    const float* D = (const float*)d_in[0];
    float* out = (float*)d_out;
    float* ws = (float*)d_ws;
    const int B = in_sizes[0] / (MM * NN);   // 64

    hipMemsetAsync(d_out, 0, (size_t)out_size * sizeof(float), stream);
    dtw_fused<<<dim3(B), dim3(NL), 0, stream>>>(D, out, ws, 1.0f / (float)B);
}

// Round 6
// 364.609 us; speedup vs baseline: 3.7328x; 1.5183x over previous
//
#include <hip/hip_runtime.h>

// Soft-DTW gradient, batch=64, 256x256, gamma=0.01 — single fused kernel.
// One 64-lane wave per batch element; lane t owns rows 4t+1..4t+4 (1-based).
// 4-column skew (wave-uniform phase): lane t processes column-group g at
// macro-step m = g + t (fwd) / m = 126 - g - t (bwd).
// Forward stores softmin weights (wl, wu) planes; backward is pure FMA and
// writes E with plain float4 stores IN-PLACE over the consumed Wl plane.
// Then: device-scope flag barrier (all 64 blocks co-resident on 256 CUs),
// each wave reduces one 1024-word slice of out across the 64 E planes.
// Zero contended atomics. 3-phase rotating prefetch buffers (no copies).
// ws: Wl/E planes [64][65536] f32, Wu planes [64][65536] f32, counter u32.

#define MM 256
#define NN 256
#define R 4
#define NL 64
#define NB 64
#define BIGV 1.0e10f
#define K2   144.269504089f     // (1/gamma) * log2(e)
#define GLN2 0.00693147181f     // gamma * ln(2)

__device__ __forceinline__ float f4get(const float4& v, int k) {
    switch (k) { case 0: return v.x; case 1: return v.y; case 2: return v.z; default: return v.w; }
}
__device__ __forceinline__ int iclamp(int x, int lo, int hi) {
    return x < lo ? lo : (x > hi ? hi : x);
}
__device__ __forceinline__ float fast_rcp(float x) {
#if __has_builtin(__builtin_amdgcn_rcpf)
    return __builtin_amdgcn_rcpf(x);
#else
    return 1.0f / x;
#endif
}

__global__ __launch_bounds__(64) void dtw_fused(
    const float* __restrict__ D,
    float* __restrict__ out,          // [256][256]
    float* __restrict__ ws)
{
    const int b = blockIdx.x;
    const int t = threadIdx.x;                       // lane 0..63
    const float* __restrict__ th = D + (size_t)b * (MM * NN);
    float* __restrict__ Wl = ws + (size_t)b * (MM * NN);               // becomes E plane
    float* __restrict__ Wu = ws + (size_t)NB * (MM * NN) + (size_t)b * (MM * NN);
    unsigned* ctr = (unsigned*)(ws + (size_t)2 * NB * (MM * NN));

    // ---------------- forward ----------------
    {
        float vprev[R];
        #pragma unroll
        for (int r = 0; r < R; ++r) vprev[r] = BIGV;
        float4 rec = make_float4(BIGV, BIGV, BIGV, BIGV);
        float prevW = BIGV;
        float botV[4] = {BIGV, BIGV, BIGV, BIGV};
        float4 thB[3][R];
        #pragma unroll
        for (int p = 0; p < 3; ++p)
            #pragma unroll
            for (int r = 0; r < R; ++r) thB[p][r] = make_float4(0.f, 0.f, 0.f, 0.f);

        auto fwd_body = [&](const int LD, const int CU, const int m) {
            const int g = m - t;
            const int gl = iclamp(g + 2, 0, 63);
            #pragma unroll
            for (int r = 0; r < R; ++r)
                thB[LD][r] = *(const float4*)(th + (4 * t + r) * NN + 4 * gl);
            if (g >= 0 && g <= 63) {
                float4 topV = rec;
                if (t == 0) topV = make_float4(BIGV, BIGV, BIGV, BIGV);
                const float vd0 = (t == 0) ? ((g == 0) ? 0.0f : BIGV)
                                           : ((g == 0) ? BIGV : prevW);
                float wlb[R][4], wub[R][4];
                #pragma unroll
                for (int cc = 0; cc < 4; ++cc) {
                    float vu = f4get(topV, cc);
                    float vd = (cc == 0) ? vd0 : f4get(topV, cc - 1);
                    #pragma unroll
                    for (int r = 0; r < R; ++r) {
                        const float vl = vprev[r];
                        const float mn = fminf(vl, fminf(vd, vu));
                        const float el = exp2f((mn - vl) * K2);
                        const float ed = exp2f((mn - vd) * K2);
                        const float eu = exp2f((mn - vu) * K2);
                        const float ss = el + ed + eu;
                        const float ri = fast_rcp(ss);
                        const float a  = mn - GLN2 * log2f(ss);
                        const float v  = a + f4get(thB[CU][r], cc);
                        wlb[r][cc] = el * ri;
                        wub[r][cc] = eu * ri;
                        vd = vl;
                        vu = v;
                        vprev[r] = v;
                    }
                    botV[cc] = vprev[R - 1];
                }
                #pragma unroll
                for (int r = 0; r < R; ++r) {
                    *(float4*)(Wl + (4 * t + r) * NN + 4 * g) =
                        make_float4(wlb[r][0], wlb[r][1], wlb[r][2], wlb[r][3]);
                    *(float4*)(Wu + (4 * t + r) * NN + 4 * g) =
                        make_float4(wub[r][0], wub[r][1], wub[r][2], wub[r][3]);
                }
            }
            prevW = rec.w;
            rec.x = __shfl_up(botV[0], 1);
            rec.y = __shfl_up(botV[1], 1);
            rec.z = __shfl_up(botV[2], 1);
            rec.w = __shfl_up(botV[3], 1);
        };
        for (int k = 0; k < 129; k += 3) {      // m = k-2 : loads land 2 iters ahead
            fwd_body(0, 1, k - 2);
            fwd_body(1, 2, k - 1);
            fwd_body(2, 0, k);
        }
    }

    __threadfence();   // order forward weight-stores before backward loads

    // ---------------- backward (pure FMA, E -> Wl plane in place) ----------------
    {
        float eprev[R], prevWl[R], prevWu[R];
        #pragma unroll
        for (int r = 0; r < R; ++r) { eprev[r] = 0.0f; prevWl[r] = 0.0f; prevWu[r] = 0.0f; }
        float4 WlB[3][R], WuB[3][R];
        #pragma unroll
        for (int p = 0; p < 3; ++p)
            #pragma unroll
            for (int r = 0; r < R; ++r) {
                WlB[p][r] = make_float4(0.f, 0.f, 0.f, 0.f);
                WuB[p][r] = make_float4(0.f, 0.f, 0.f, 0.f);
            }
        float4 recWd = make_float4(0.f, 0.f, 0.f, 0.f);
        float4 recWu = recWd, recE = recWd;
        float pWd = 0.0f, pE = 0.0f;
        float topWd[4] = {0.f, 0.f, 0.f, 0.f};
        float topWu[4] = {0.f, 0.f, 0.f, 0.f};
        float topE[4]  = {0.f, 0.f, 0.f, 0.f};

        auto bwd_body = [&](const int LD, const int CU, const int m) {
            const int g = 126 - m - t;
            const int gl = iclamp(g - 2, 0, 63);
            #pragma unroll
            for (int r = 0; r < R; ++r) {
                WlB[LD][r] = *(const float4*)(Wl + (4 * t + r) * NN + 4 * gl);
                WuB[LD][r] = *(const float4*)(Wu + (4 * t + r) * NN + 4 * gl);
            }
            if (g >= 0 && g <= 63) {
                float4 rWd = recWd, rWu = recWu, rE = recE;
                if (t == NL - 1) {
                    rWd = make_float4(0.f, 0.f, 0.f, 0.f); rWu = rWd; rE = rWd;
                }
                const float pWd_ = (g == 63 || t == NL - 1) ? 0.0f : pWd;
                const float pE_  = (g == 63 || t == NL - 1) ? 0.0f : pE;
                float ebuf[R][4];
                #pragma unroll
                for (int cc = 3; cc >= 0; --cc) {
                    float bWd = (cc == 3) ? pWd_ : f4get(rWd, cc + 1);
                    float bEo = (cc == 3) ? pE_  : f4get(rE,  cc + 1);
                    float bWu = f4get(rWu, cc);
                    float bEn = f4get(rE,  cc);
                    #pragma unroll
                    for (int r = R - 1; r >= 0; --r) {
                        const float wlr = (cc == 3) ? prevWl[r] : f4get(WlB[CU][r], cc + 1);
                        float e = wlr * eprev[r] + bWd * bEo + bWu * bEn;
                        if (t == NL - 1 && r == R - 1 && g == 63 && cc == 3)
                            e = 1.0f;                                   // seed E(M,N)
                        ebuf[r][cc] = e;
                        const float wu_b = (cc == 3) ? prevWu[r] : f4get(WuB[CU][r], cc + 1);
                        bWd = 1.0f - wlr - wu_b;
                        bWu = f4get(WuB[CU][r], cc);
                        bEo = eprev[r];
                        bEn = e;
                        eprev[r] = e;
                    }
                }
                #pragma unroll
                for (int cc = 0; cc < 4; ++cc) {
                    topWd[cc] = 1.0f - f4get(WlB[CU][0], cc) - f4get(WuB[CU][0], cc);
                    topWu[cc] = f4get(WuB[CU][0], cc);
                    topE[cc]  = ebuf[0][cc];
                }
                #pragma unroll
                for (int r = 0; r < R; ++r)                     // E in place of Wl
                    *(float4*)(Wl + (4 * t + r) * NN + 4 * g) =
                        make_float4(ebuf[r][0], ebuf[r][1], ebuf[r][2], ebuf[r][3]);
            }
            pWd = recWd.x; pE = recE.x;
            #pragma unroll
            for (int r = 0; r < R; ++r) { prevWl[r] = WlB[CU][r].x; prevWu[r] = WuB[CU][r].x; }
            recWd.x = __shfl_down(topWd[0], 1);
            recWd.y = __shfl_down(topWd[1], 1);
            recWd.z = __shfl_down(topWd[2], 1);
            recWd.w = __shfl_down(topWd[3], 1);
            recWu.x = __shfl_down(topWu[0], 1);
            recWu.y = __shfl_down(topWu[1], 1);
            recWu.z = __shfl_down(topWu[2], 1);
            recWu.w = __shfl_down(topWu[3], 1);
            recE.x  = __shfl_down(topE[0], 1);
            recE.y  = __shfl_down(topE[1], 1);
            recE.z  = __shfl_down(topE[2], 1);
            recE.w  = __shfl_down(topE[3], 1);
        };
        for (int k = 0; k < 129; k += 3) {
            bwd_body(0, 1, k - 2);
            bwd_body(1, 2, k - 1);
            bwd_body(2, 0, k);
        }
    }

    // ---------------- device-scope barrier + slice reduction ----------------
    __threadfence();                               // release E stores (L2 writeback)
    if (t == 0)
        __hip_atomic_fetch_add(ctr, 1u, __ATOMIC_ACQ_REL, __HIP_MEMORY_SCOPE_AGENT);
    unsigned cnt;
    do {
        cnt = __hip_atomic_load(ctr, __ATOMIC_ACQUIRE, __HIP_MEMORY_SCOPE_AGENT);
        if (cnt < NB) __builtin_amdgcn_s_sleep(2);
    } while (cnt < NB);
    __builtin_amdgcn_fence(__ATOMIC_ACQUIRE, "agent");   // invalidate L1/L2

    {
        const float* Eall = ws;                    // Wl planes now hold E
        float4 acc[4];
        #pragma unroll
        for (int k2 = 0; k2 < 4; ++k2) acc[k2] = make_float4(0.f, 0.f, 0.f, 0.f);
        for (int p = 0; p < NB; ++p) {
            const float* Ep = Eall + (size_t)p * (MM * NN);
            #pragma unroll
            for (int k2 = 0; k2 < 4; ++k2) {
                const float4 v = *(const float4*)(Ep + 1024 * b + 256 * k2 + 4 * t);
                acc[k2].x += v.x; acc[k2].y += v.y; acc[k2].z += v.z; acc[k2].w += v.w;
            }
        }
        const float inv = 1.0f / (float)NB;
        #pragma unroll
        for (int k2 = 0; k2 < 4; ++k2)
            *(float4*)(out + 1024 * b + 256 * k2 + 4 * t) =
                make_float4(acc[k2].x * inv, acc[k2].y * inv, acc[k2].z * inv, acc[k2].w * inv);
    }
}

extern "C" void kernel_launch(void* const* d_in, const int* in_sizes, int n_in,
                              void* d_out, int out_size, void* d_ws, size_t ws_size,
                              hipStream_t stream) {
    const float* D = (const float*)d_in[0];
    float* out = (float*)d_out;
    float* ws = (float*)d_ws;

    // zero the barrier counter (ws is re-poisoned 0xAA before every launch)
    hipMemsetAsync(ws + (size_t)2 * NB * (MM * NN), 0, sizeof(unsigned), stream);
    dtw_fused<<<dim3(NB), dim3(NL), 0, stream>>>(D, out, ws);
}